// Round 1
// baseline (731.149 us; speedup 1.0000x reference)
//
#include <hip/hip_runtime.h>

// WaveCell: 2D scalar wave equation, 5-point Laplacian, absorbing-boundary
// damping, point source at (96,32). B=4 batches, T=256 sequential steps,
// 192x192 grid. Output [B, T, NX, NY] fp32.
//
// Baseline structure: prep kernel (coefficients) + 256 chained step kernels.
// y(t-1), y(t-2) are read straight out of the output tensor, so no extra
// field state is carried in workspace.

#define NXg 192
#define NYg 192
#define BATCH 4
#define TSTEPS 256
#define CELLS (NXg * NYg)          // 36864
#define FIELD (BATCH * CELLS)      // 147456

__global__ __launch_bounds__(256) void prep_kernel(
    const float* __restrict__ c, const float* __restrict__ b,
    float* __restrict__ a_inv, float* __restrict__ coef2,
    float* __restrict__ c2) {
  int i = blockIdx.x * blockDim.x + threadIdx.x;
  if (i < CELLS) {
    float bb = b[i];
    // inv_dt2 = 1/dt^2 = 1e6 ; 0.5*b/dt = 500*b
    a_inv[i] = 1.0f / (1.0e6f + 500.0f * bb);
    coef2[i] = 1.0e6f - 500.0f * bb;
    float cc = c[i];
    c2[i] = cc * cc;
  }
}

__global__ __launch_bounds__(256) void step_kernel(
    const float* __restrict__ a_inv, const float* __restrict__ coef2,
    const float* __restrict__ c2, const float* __restrict__ x,
    float* __restrict__ out, int t) {
  int idx = blockIdx.x * blockDim.x + threadIdx.x;
  if (idx >= FIELD) return;
  int cell = idx % CELLS;
  int bidx = idx / CELLS;
  int iy = cell % NYg;
  int ix = cell / NYg;

  // inv_h2 = 1/(dt^2 * 2 * 1.01^2); dt=1e-3 -> 1/(2.0402e-6)
  const float inv_h2 = (float)(1.0 / (2.0 * 1.01 * 1.01 * 1.0e-3 * 1.0e-3));

  const long bt = (long)bidx * TSTEPS * CELLS;
  const float* y1p = out + bt + (long)(t - 1) * CELLS;
  const float* y2p = out + bt + (long)(t - 2) * CELLS;

  float v1 = 0.0f, v2 = 0.0f;
  float up = 0.0f, dn = 0.0f, lf = 0.0f, rt = 0.0f;
  if (t >= 1) {
    v1 = y1p[cell];
    up = (ix > 0) ? y1p[cell - NYg] : 0.0f;
    dn = (ix < NXg - 1) ? y1p[cell + NYg] : 0.0f;
    lf = (iy > 0) ? y1p[cell - 1] : 0.0f;
    rt = (iy < NYg - 1) ? y1p[cell + 1] : 0.0f;
  }
  if (t >= 2) {
    v2 = y2p[cell];
  }

  float lap = inv_h2 * (up + dn + lf + rt - 4.0f * v1);
  float y = a_inv[cell] * (2.0e6f * v1 - coef2[cell] * v2 + c2[cell] * lap);

  if (ix == 96 && iy == 32) {
    y += x[bidx * TSTEPS + t];  // x is [B, T, 1]
  }

  out[bt + (long)t * CELLS + cell] = y;
}

extern "C" void kernel_launch(void* const* d_in, const int* in_sizes, int n_in,
                              void* d_out, int out_size, void* d_ws,
                              size_t ws_size, hipStream_t stream) {
  const float* x = (const float*)d_in[0];  // [B, T, 1] = 1024
  const float* c = (const float*)d_in[1];  // [192,192]
  const float* b = (const float*)d_in[2];  // [192,192]
  float* out = (float*)d_out;              // [B, T, 192, 192]

  float* a_inv = (float*)d_ws;
  float* coef2 = a_inv + CELLS;
  float* c2 = coef2 + CELLS;

  prep_kernel<<<(CELLS + 255) / 256, 256, 0, stream>>>(c, b, a_inv, coef2, c2);

  const int blocks = (FIELD + 255) / 256;  // 576
  for (int t = 0; t < TSTEPS; ++t) {
    step_kernel<<<blocks, 256, 0, stream>>>(a_inv, coef2, c2, x, out, t);
  }
}

// Round 2
// 429.437 us; speedup vs baseline: 1.7026x; 1.7026x over previous
//
#include <hip/hip_runtime.h>

// WaveCell: 2D wave equation, temporal blocking k=16.
// Each block owns a 24x24 output tile, computes on a 56x56 extended region
// (halo = k) held in LDS ping-pong buffers. y(t-2) and per-cell coefficients
// live in registers (pointwise access only). Valid region shrinks by 1 per
// sub-step, so blocks are fully independent within a launch. 16 launches + prep.

#define NXg 192
#define NYg 192
#define BATCH 4
#define TSTEPS 256
#define CELLS (NXg * NYg)

#define TS 24                  // output tile side
#define KSTEP 16               // time steps per launch
#define EXT (TS + 2 * KSTEP)   // 56 extended tile side
#define E2 (EXT * EXT)         // 3136
#define PITCH (EXT + 1)        // 57 (LDS bank-conflict pad)
#define NTHREADS 512
#define NPT ((E2 + NTHREADS - 1) / NTHREADS)  // 7 cells/thread

#define SRC_X 96
#define SRC_Y 32

__global__ __launch_bounds__(256) void prep_kernel(
    const float* __restrict__ c, const float* __restrict__ b,
    float* __restrict__ a_inv, float* __restrict__ coef2,
    float* __restrict__ c2) {
  int i = blockIdx.x * blockDim.x + threadIdx.x;
  if (i < CELLS) {
    float bb = b[i];
    a_inv[i] = 1.0f / (1.0e6f + 500.0f * bb);
    coef2[i] = 1.0e6f - 500.0f * bb;
    float cc = c[i];
    c2[i] = cc * cc;
  }
}

__global__ __launch_bounds__(NTHREADS, 2) void wave_tile_kernel(
    const float* __restrict__ a_inv_g, const float* __restrict__ coef2_g,
    const float* __restrict__ c2_g, const float* __restrict__ x,
    float* __restrict__ out, int t0) {
  __shared__ float buf0[EXT * PITCH];
  __shared__ float buf1[EXT * PITCH];

  const int tid = threadIdx.x;
  const int bcol = blockIdx.x;  // 0..7
  const int brow = blockIdx.y;  // 0..7
  const int b = blockIdx.z;     // 0..3
  const int r0 = brow * TS - KSTEP;  // global row of local row 0
  const int c0 = bcol * TS - KSTEP;

  const float inv_h2 = (float)(1.0 / (2.0 * 1.01 * 1.01 * 1.0e-3 * 1.0e-3));
  const long obase = (long)b * TSTEPS * CELLS;

  // zero both buffers (out-of-domain cells must read as 0 forever)
  for (int i = tid; i < EXT * PITCH; i += NTHREADS) {
    buf0[i] = 0.0f;
    buf1[i] = 0.0f;
  }

  // Per-cell static state in registers.
  float yc[NPT], yp[NPT];              // y(t-1), y(t-2) at own cell
  float ai[NPT], cf[NPT], cs[NPT];     // a_inv, coef2, c2
  int lofs[NPT];                       // LDS offset (pitch 57)
  int gidx[NPT];                       // global cell index r*192+c
  int dmin[NPT];                       // distance to extended-region edge
  bool indom[NPT], intile[NPT], issrc[NPT];

#pragma unroll
  for (int it = 0; it < NPT; ++it) {
    int li = tid + it * NTHREADS;
    float ycv = 0.f, ypv = 0.f, av = 0.f, fv = 0.f, sv = 0.f;
    int lof = 0, gi = 0, dm = -1;
    bool id = false, til = false, src = false;
    if (li < E2) {
      int lr = li / EXT, lc = li % EXT;
      lof = lr * PITCH + lc;
      int gr = r0 + lr, gc = c0 + lc;
      id = (gr >= 0 && gr < NXg && gc >= 0 && gc < NYg);
      int d1 = lr < (EXT - 1 - lr) ? lr : (EXT - 1 - lr);
      int d2 = lc < (EXT - 1 - lc) ? lc : (EXT - 1 - lc);
      dm = d1 < d2 ? d1 : d2;
      til = (lr >= KSTEP && lr < KSTEP + TS && lc >= KSTEP && lc < KSTEP + TS);
      if (id) {
        gi = gr * NYg + gc;
        src = (gr == SRC_X && gc == SRC_Y);
        av = a_inv_g[gi];
        fv = coef2_g[gi];
        sv = c2_g[gi];
        if (t0 > 0) {
          ycv = out[obase + (long)(t0 - 1) * CELLS + gi];
          if (t0 > 1) ypv = out[obase + (long)(t0 - 2) * CELLS + gi];
        }
      }
    }
    yc[it] = ycv; yp[it] = ypv;
    ai[it] = av; cf[it] = fv; cs[it] = sv;
    lofs[it] = lof; gidx[it] = gi; dmin[it] = dm;
    indom[it] = id; intile[it] = til; issrc[it] = src;
  }
  __syncthreads();  // ensure zero-fill done before scatter of loaded values

#pragma unroll
  for (int it = 0; it < NPT; ++it) {
    int li = tid + it * NTHREADS;
    if (li < E2 && indom[it]) buf0[lofs[it]] = yc[it];
  }
  __syncthreads();

  float* ping = buf0;
  float* pong = buf1;

  for (int j = 0; j < KSTEP; ++j) {
    const int lo = j + 1;  // valid iff dmin >= lo
    const int t = t0 + j;
#pragma unroll
    for (int it = 0; it < NPT; ++it) {
      int li = tid + it * NTHREADS;
      if (li < E2 && indom[it] && dmin[it] >= lo) {
        int lof = lofs[it];
        float up = ping[lof - PITCH];
        float dn = ping[lof + PITCH];
        float lf = ping[lof - 1];
        float rt = ping[lof + 1];
        float v1 = yc[it];
        float lap = inv_h2 * (up + dn + lf + rt - 4.0f * v1);
        float val = ai[it] * (2.0e6f * v1 - cf[it] * yp[it] + cs[it] * lap);
        if (issrc[it]) val += x[b * TSTEPS + t];
        yp[it] = v1;
        yc[it] = val;
        pong[lof] = val;
        if (intile[it]) {
          out[obase + (long)t * CELLS + gidx[it]] = val;
        }
      }
    }
    __syncthreads();  // separates this step's reads of `ping` from next
                      // step's writes into it (after swap)
    float* tmp = ping; ping = pong; pong = tmp;
  }
}

extern "C" void kernel_launch(void* const* d_in, const int* in_sizes, int n_in,
                              void* d_out, int out_size, void* d_ws,
                              size_t ws_size, hipStream_t stream) {
  const float* x = (const float*)d_in[0];  // [B, T, 1]
  const float* c = (const float*)d_in[1];  // [192,192]
  const float* b = (const float*)d_in[2];  // [192,192]
  float* out = (float*)d_out;              // [B, T, 192, 192]

  float* a_inv = (float*)d_ws;
  float* coef2 = a_inv + CELLS;
  float* c2 = coef2 + CELLS;

  prep_kernel<<<(CELLS + 255) / 256, 256, 0, stream>>>(c, b, a_inv, coef2, c2);

  dim3 grid(NXg / TS, NYg / TS, BATCH);  // 8 x 8 x 4 = 256 blocks
  for (int t0 = 0; t0 < TSTEPS; t0 += KSTEP) {
    wave_tile_kernel<<<grid, NTHREADS, 0, stream>>>(a_inv, coef2, c2, x, out, t0);
  }
}

// Round 3
// 367.535 us; speedup vs baseline: 1.9893x; 1.1684x over previous
//
#include <hip/hip_runtime.h>

// WaveCell: temporal blocking k=16, 1x4 float4 patches, zero guard ring,
// NO inner-loop predication (shrinking-region invariant: a cell at edge
// distance d is never read after sub-step d, and out-of-domain cells have
// a_inv=0 so they self-zero). 16 launches, no prep kernel.

#define NXg 192
#define NYg 192
#define BATCH 4
#define TSTEPS 256
#define CELLS (NXg * NYg)

#define TS 24                   // output tile side
#define KSTEP 16                // time steps per launch
#define EXT 56                  // TS + 2*KSTEP
#define GROW 14                 // float4 groups per row (EXT/4)
#define NP (EXT * GROW)         // 784 patches per block
#define LROWS (EXT + 2)         // +1 guard row top/bottom
#define LPITCH 64               // dwords; 4 guard cols left, 4 right
#define LSZ (LROWS * LPITCH)    // 3712 dwords = 14.5 KB per buffer
#define NTHREADS 512
#define NPT 2                   // patches per thread

#define SRC_X 96
#define SRC_Y 32

__global__ __launch_bounds__(NTHREADS) void wave_tile_kernel(
    const float* __restrict__ cg, const float* __restrict__ bg,
    const float* __restrict__ x, float* __restrict__ out, int t0) {
  __shared__ float buf0[LSZ];
  __shared__ float buf1[LSZ];

  const int tid = threadIdx.x;
  const int bcol = blockIdx.x;  // 0..7
  const int brow = blockIdx.y;  // 0..7
  const int bb = blockIdx.z;    // 0..3
  const int r0 = brow * TS - KSTEP;
  const int c0 = bcol * TS - KSTEP;
  const int obase = bb * TSTEPS * CELLS;
  const float inv_h2 = (float)(1.0 / (2.0 * 1.01 * 1.01 * 1.0e-3 * 1.0e-3));

  // Zero both LDS buffers (guard ring must read as 0; interior overwritten).
  {
    float4 z = make_float4(0.f, 0.f, 0.f, 0.f);
    float4* p0 = (float4*)buf0;
    float4* p1 = (float4*)buf1;
    for (int i = tid; i < LSZ / 4; i += NTHREADS) {
      p0[i] = z;
      p1[i] = z;
    }
  }

  // Preload the 16 source samples for this time chunk (t0 multiple of 16).
  float xs[KSTEP];
  {
    const float4* xp = (const float4*)(x + bb * TSTEPS + t0);
    float4 a0 = xp[0], a1 = xp[1], a2 = xp[2], a3 = xp[3];
    xs[0] = a0.x; xs[1] = a0.y; xs[2] = a0.z; xs[3] = a0.w;
    xs[4] = a1.x; xs[5] = a1.y; xs[6] = a1.z; xs[7] = a1.w;
    xs[8] = a2.x; xs[9] = a2.y; xs[10] = a2.z; xs[11] = a2.w;
    xs[12] = a3.x; xs[13] = a3.y; xs[14] = a3.z; xs[15] = a3.w;
  }

  // Per-patch static state.
  float4 yc[NPT], yp[NPT], ai[NPT], cf[NPT], cs[NPT], sm[NPT];
  int loff[NPT], gofs[NPT];
  bool act[NPT], til[NPT];

#pragma unroll
  for (int it = 0; it < NPT; ++it) {
    const int p = tid + it * NTHREADS;
    const float4 z = make_float4(0.f, 0.f, 0.f, 0.f);
    yc[it] = z; yp[it] = z; ai[it] = z; cf[it] = z; cs[it] = z; sm[it] = z;
    loff[it] = LPITCH + 4; gofs[it] = 0; til[it] = false;
    act[it] = (p < NP);
    if (act[it]) {
      const int lr = p / GROW;
      const int lg = p % GROW;
      loff[it] = (lr + 1) * LPITCH + 4 + lg * 4;
      const int gr = r0 + lr;
      const int gc = c0 + lg * 4;  // multiple of 4; groups never straddle domain edge
      til[it] = (lr >= KSTEP && lr < KSTEP + TS && lg >= 4 && lg < 10);
      if (gr >= 0 && gr < NXg && gc >= 0 && gc < NYg) {
        const int gi = gr * NYg + gc;
        gofs[it] = gi;
        float4 cv = *(const float4*)(cg + gi);
        float4 bv = *(const float4*)(bg + gi);
        ai[it].x = 1.0f / (1.0e6f + 500.0f * bv.x);
        ai[it].y = 1.0f / (1.0e6f + 500.0f * bv.y);
        ai[it].z = 1.0f / (1.0e6f + 500.0f * bv.z);
        ai[it].w = 1.0f / (1.0e6f + 500.0f * bv.w);
        cf[it].x = 1.0e6f - 500.0f * bv.x;
        cf[it].y = 1.0e6f - 500.0f * bv.y;
        cf[it].z = 1.0e6f - 500.0f * bv.z;
        cf[it].w = 1.0e6f - 500.0f * bv.w;
        cs[it].x = cv.x * cv.x;
        cs[it].y = cv.y * cv.y;
        cs[it].z = cv.z * cv.z;
        cs[it].w = cv.w * cv.w;
        if (t0 > 0) {
          yc[it] = *(const float4*)(out + obase + (t0 - 1) * CELLS + gi);
          yp[it] = *(const float4*)(out + obase + (t0 - 2) * CELLS + gi);
        }
        if (gr == SRC_X && SRC_Y >= gc && SRC_Y < gc + 4) {
          ((float*)&sm[it])[SRC_Y - gc] = 1.0f;
        }
      }
    }
  }

  __syncthreads();  // zero-fill complete before interior scatter

#pragma unroll
  for (int it = 0; it < NPT; ++it) {
    if (act[it]) *(float4*)&buf0[loff[it]] = yc[it];
  }
  __syncthreads();

  float* ping = buf0;
  float* pong = buf1;

#pragma unroll
  for (int j = 0; j < KSTEP; ++j) {
    const float xt = xs[j];
    float* op = out + obase + (t0 + j) * CELLS;
#pragma unroll
    for (int it = 0; it < NPT; ++it) {
      if (act[it]) {
        const int lo = loff[it];
        float4 up = *(float4*)&ping[lo - LPITCH];
        float4 dn = *(float4*)&ping[lo + LPITCH];
        float4 lq = *(float4*)&ping[lo - 4];   // need only .w (left of elem 0)
        float4 rq = *(float4*)&ping[lo + 4];   // need only .x (right of elem 3)
        float4 v1 = yc[it];
        float4 vp = yp[it];
        float4 av = ai[it], fv = cf[it], sv = cs[it], smv = sm[it];
        float4 val;
        {
          float lap = inv_h2 * (up.x + dn.x + lq.w + v1.y - 4.0f * v1.x);
          val.x = av.x * (2.0e6f * v1.x - fv.x * vp.x + sv.x * lap) + smv.x * xt;
        }
        {
          float lap = inv_h2 * (up.y + dn.y + v1.x + v1.z - 4.0f * v1.y);
          val.y = av.y * (2.0e6f * v1.y - fv.y * vp.y + sv.y * lap) + smv.y * xt;
        }
        {
          float lap = inv_h2 * (up.z + dn.z + v1.y + v1.w - 4.0f * v1.z);
          val.z = av.z * (2.0e6f * v1.z - fv.z * vp.z + sv.z * lap) + smv.z * xt;
        }
        {
          float lap = inv_h2 * (up.w + dn.w + v1.z + rq.x - 4.0f * v1.w);
          val.w = av.w * (2.0e6f * v1.w - fv.w * vp.w + sv.w * lap) + smv.w * xt;
        }
        yp[it] = v1;
        yc[it] = val;
        *(float4*)&pong[lo] = val;
        if (til[it]) *(float4*)(op + gofs[it]) = val;
      }
    }
    __syncthreads();
    float* tmp = ping; ping = pong; pong = tmp;
  }
}

extern "C" void kernel_launch(void* const* d_in, const int* in_sizes, int n_in,
                              void* d_out, int out_size, void* d_ws,
                              size_t ws_size, hipStream_t stream) {
  const float* x = (const float*)d_in[0];  // [B, T, 1]
  const float* c = (const float*)d_in[1];  // [192,192]
  const float* b = (const float*)d_in[2];  // [192,192]
  float* out = (float*)d_out;              // [B, T, 192, 192]

  dim3 grid(NXg / TS, NYg / TS, BATCH);  // 8 x 8 x 4 = 256 blocks
  for (int t0 = 0; t0 < TSTEPS; t0 += KSTEP) {
    wave_tile_kernel<<<grid, NTHREADS, 0, stream>>>(c, b, x, out, t0);
  }
}